// Round 2
// baseline (289.242 us; speedup 1.0000x reference)
//
#include <hip/hip_runtime.h>
#include <stdint.h>

#define TLEN  4096
#define BATCH 128
#define NG    6      // pair-groups: 2 joint-pairs (4 joints, 32 co) each
#define TT    256    // output t per block

typedef short short8 __attribute__((ext_vector_type(8)));
typedef float f32x16 __attribute__((ext_vector_type(16)));
typedef unsigned int uint;

__device__ __forceinline__ unsigned short f2bf(float f) {
    unsigned int u = __float_as_uint(f);
    u += 0x7fffu + ((u >> 16) & 1u);
    return (unsigned short)(u >> 16);
}

// Masked bf16 weight fragments wf[g][co_l(32)][m(48)][j(8)].
// K index kk = 8*m + j with k_tap = m&15, ci_l = 8*(m>>4)+j  (24 ci union,
// k padded 15->16). Zero outside skeleton mask / bounds / k==15.
__global__ __launch_bounds__(256) void prep2(
    const float* __restrict__ w, unsigned short* __restrict__ wf)
{
    int e = blockIdx.x * 256 + threadIdx.x;      // 6*32*48*8 = 73728
    int j  = e & 7;
    int t  = e >> 3;
    int m  = t % 48;
    t      = t / 48;
    int co = t & 31;
    int g  = t >> 5;
    int k  = m & 15;
    int ci = 8 * (m >> 4) + j;                   // 0..23
    int jo = 4 * g + (co >> 3);
    int jn = 4 * g - 1 + (ci >> 2);
    int cig = 16 * g - 4 + ci;
    float v = 0.f;
    if (k < 15 && jn >= 0 && jn < 24 && jn >= jo - 1 && jn <= jo + 1)
        v = w[((size_t)(32 * g + co) * 96 + cig) * 15 + k];
    wf[e] = f2bf(v);
}

__global__ void skel2(const float* __restrict__ x, const unsigned short* __restrict__ wf,
                      const float* __restrict__ bias, float* __restrict__ out)
{
    // x tile: [row 272][ci 24 -> padded 32] bf16, 64B rows,
    // 16B-unit XOR swizzle: physical_unit = u ^ ((row>>1)&3)
    __shared__ __align__(16) unsigned short xlds[272 * 32];

    const int tid  = threadIdx.x;
    const int t0   = blockIdx.x * TT;
    const int g    = blockIdx.y;
    const int b    = blockIdx.z;
    const int lane = tid & 63;
    const int wave = tid >> 6;
    const int col  = lane & 31;     // A row(co) / B,D col(t)
    const int h    = lane >> 5;     // K-half

    // ---- A fragments in registers, issued early (L2-hot, 24 x b128) ----
    short8 afrag[24];
    {
        const unsigned short* wp = wf + ((size_t)(g * 32 + col) * 48 + h) * 8;
        #pragma unroll
        for (int s = 0; s < 24; ++s)
            afrag[s] = *reinterpret_cast<const short8*>(wp + s * 16);
    }

    // ---- stage x tile: lane = t-row, coalesced dword loads over 24 ci ----
    {
        const int ciBase = 16 * g - 4;
        const float* xb = x + (size_t)b * 96 * TLEN;
        for (int r = tid; r < 272; r += 256) {
            uint vals[12];
            if (r < 270) {
                int tg = t0 - 7 + r;
                int src = tg < 0 ? -tg : (tg >= TLEN ? 2 * TLEN - 2 - tg : tg);
                const float* xs = xb + src;
                #pragma unroll
                for (int q = 0; q < 12; ++q) {
                    int c0 = ciBase + 2 * q;
                    int c1 = c0 + 1;
                    float f0 = ((unsigned)c0 < 96u) ? xs[(size_t)c0 * TLEN] : 0.f;
                    float f1 = ((unsigned)c1 < 96u) ? xs[(size_t)c1 * TLEN] : 0.f;
                    vals[q] = (uint)f2bf(f0) | ((uint)f2bf(f1) << 16);
                }
            } else {
                #pragma unroll
                for (int q = 0; q < 12; ++q) vals[q] = 0u;
            }
            int sw = (r >> 1) & 3;
            #pragma unroll
            for (int u = 0; u < 3; ++u) {
                int pu = u ^ sw;
                uint4 wv = make_uint4(vals[4*u], vals[4*u+1], vals[4*u+2], vals[4*u+3]);
                *reinterpret_cast<uint4*>(&xlds[r * 32 + pu * 8]) = wv;
            }
        }
    }
    __syncthreads();

    // ---- MFMA: M=32 co, K=384, two 32-t tiles per wave ----
    f32x16 acc0, acc1;
    #pragma unroll
    for (int i = 0; i < 16; ++i) { acc0[i] = 0.f; acc1[i] = 0.f; }

    const int C = wave * 64 + col;        // nf0 local-t == staged-row base
    #pragma unroll
    for (int s = 0; s < 24; ++s) {
        int m = 2 * s + h;
        int k = m & 15;
        int u = m >> 4;
        int row = C + k;
        int addr = row * 32 + ((u ^ ((row >> 1) & 3)) << 3);
        short8 b0 = *reinterpret_cast<const short8*>(&xlds[addr]);
        acc0 = __builtin_amdgcn_mfma_f32_32x32x16_bf16(afrag[s], b0, acc0, 0, 0, 0);
        short8 b1 = *reinterpret_cast<const short8*>(&xlds[addr + 1024]);  // row+32, same swizzle
        acc1 = __builtin_amdgcn_mfma_f32_32x32x16_bf16(afrag[s], b1, acc1, 0, 0, 0);
    }

    // ---- epilogue: D col=t=lane&31, row=(reg&3)+8*(reg>>2)+4*h ----
    const int coBase = 32 * g + 4 * h;
    float4 bv[4];
    #pragma unroll
    for (int rq = 0; rq < 4; ++rq)
        bv[rq] = *reinterpret_cast<const float4*>(&bias[coBase + 8 * rq]);

    float* ob = out + ((size_t)b * 192 + 32 * g + 4 * h) * TLEN + t0 + wave * 64 + col;
    #pragma unroll
    for (int nf = 0; nf < 2; ++nf) {
        float* obn = ob + nf * 32;
        #pragma unroll
        for (int reg = 0; reg < 16; ++reg) {
            int rowc = (reg & 3) + 8 * (reg >> 2);            // + 4h folded into ob
            float av = nf ? acc1[reg] : acc0[reg];
            float bb = (&bv[reg >> 2].x)[reg & 3];
            obn[(size_t)rowc * TLEN] = av + bb;
        }
    }
}

extern "C" void kernel_launch(void* const* d_in, const int* in_sizes, int n_in,
                              void* d_out, int out_size, void* d_ws, size_t ws_size,
                              hipStream_t stream) {
    const float* x    = (const float*)d_in[0];
    const float* w    = (const float*)d_in[1];
    const float* bias = (const float*)d_in[2];
    float* out        = (float*)d_out;
    unsigned short* wf = (unsigned short*)d_ws;   // 147456 B

    prep2<<<dim3(288), dim3(256), 0, stream>>>(w, wf);
    skel2<<<dim3(TLEN / TT, NG, BATCH), dim3(256), 0, stream>>>(x, wf, bias, out);
}

// Round 3
// 202.226 us; speedup vs baseline: 1.4303x; 1.4303x over previous
//
#include <hip/hip_runtime.h>
#include <stdint.h>

#define TLEN  4096
#define BATCH 128
#define NPAIR 12
#define TT    256    // output t per block
#define ROWS  272    // 256 + 15 halo, rows >=270 zeroed (tap-15 pad reads)

typedef short short8 __attribute__((ext_vector_type(8)));
typedef float f32x4 __attribute__((ext_vector_type(4)));
typedef unsigned int uint;

__device__ __forceinline__ unsigned short f2bf(float f) {
    unsigned int u = __float_as_uint(f);
    u += 0x7fffu + ((u >> 16) & 1u);
    return (unsigned short)(u >> 16);
}

// Masked bf16 weight fragments: wf[p][co_l(16)][kk(256)], kk = k*16 + ci_l.
// ci_l -> joint jn = 2p-1 + ci_l/4 (4-joint union); zero outside skeleton
// mask / bounds / k==15 (taps padded 15->16).
__global__ __launch_bounds__(256) void prep_weights_kernel(
    const float* __restrict__ w, unsigned short* __restrict__ wf)
{
    int e = blockIdx.x * 256 + threadIdx.x;   // 12*16*256 = 49152
    int kk   = e & 255;
    int co_l = (e >> 8) & 15;
    int p    = e >> 12;
    int k    = kk >> 4;
    int ci_l = kk & 15;
    int jo = 2 * p + (co_l >> 3);
    int jn = 2 * p - 1 + (ci_l >> 2);
    int ci_g = 8 * p - 4 + ci_l;
    float v = 0.0f;
    if (k < 15 && jn >= 0 && jn < 24 && jn >= jo - 1 && jn <= jo + 1)
        v = w[((size_t)(16 * p + co_l) * 96 + ci_g) * 15 + k];
    wf[e] = f2bf(v);
}

__global__ __launch_bounds__(256) void skel_conv_kernel(
    const float* __restrict__ x, const unsigned short* __restrict__ wf,
    const float* __restrict__ bias, float* __restrict__ out)
{
    // x tile [row][ci 16], row stride 24 ushorts (48 B): 48B-stride rows tile
    // all eight 16B bank slots uniformly (period 8 rows over 3 x 128B).
    __shared__ __align__(16) unsigned short xlds[ROWS * 24];

    const int tid  = threadIdx.x;
    const int t0   = blockIdx.x * TT;
    const int p    = blockIdx.y;
    const int b    = blockIdx.z;
    const int lane = tid & 63;
    const int wave = tid >> 6;
    const int col  = lane & 15;     // A row (co) / B,D col (t)
    const int hi2  = lane >> 4;     // K sub-block selector

    // ---- A fragments: 8 K-slices of masked weights -> registers, PINNED ----
    short8 afrag[8];
    {
        const unsigned short* wp = wf + (size_t)(p * 16 + col) * 256 + hi2 * 8;
        #pragma unroll
        for (int s = 0; s < 8; ++s)
            afrag[s] = *reinterpret_cast<const short8*>(wp + s * 32);
    }
    // Force residency: compiler must keep these in VGPRs (cannot re-sink the
    // loads into the MFMA loop -- that was R2's failure mode, VGPR_Count=64).
    #pragma unroll
    for (int s = 0; s < 8; ++s)
        asm volatile("" : "+v"(afrag[s]));

    // ---- stage x tile: lane = t-row, coalesced dword loads over 16 ci ----
    {
        const int ciBase = 8 * p - 4;
        const float* xb = x + (size_t)b * 96 * TLEN;
        for (int r = tid; r < ROWS; r += 256) {
            uint vals[8];
            if (r < 270) {
                int tg = t0 - 7 + r;
                int src = tg < 0 ? -tg : (tg >= TLEN ? 2 * TLEN - 2 - tg : tg);
                const float* xs = xb + src;
                #pragma unroll
                for (int q = 0; q < 8; ++q) {
                    int c0 = ciBase + 2 * q;
                    int c1 = c0 + 1;
                    float f0 = ((unsigned)c0 < 96u) ? xs[(size_t)c0 * TLEN] : 0.f;
                    float f1 = ((unsigned)c1 < 96u) ? xs[(size_t)c1 * TLEN] : 0.f;
                    vals[q] = (uint)f2bf(f0) | ((uint)f2bf(f1) << 16);
                }
            } else {
                #pragma unroll
                for (int q = 0; q < 8; ++q) vals[q] = 0u;
            }
            *reinterpret_cast<uint4*>(&xlds[r * 24 + 0]) =
                make_uint4(vals[0], vals[1], vals[2], vals[3]);
            *reinterpret_cast<uint4*>(&xlds[r * 24 + 8]) =
                make_uint4(vals[4], vals[5], vals[6], vals[7]);
        }
    }
    __syncthreads();

    const int ci0b = (hi2 & 1) * 8;   // ci base for this lane's B elements
    const int kb   = hi2 >> 1;        // k-tap low bit

    f32x4 acc[4];
    #pragma unroll
    for (int nf = 0; nf < 4; ++nf) acc[nf] = (f32x4){0.f, 0.f, 0.f, 0.f};

    #pragma unroll
    for (int nf = 0; nf < 4; ++nf) {
        const int ntl = wave * 64 + nf * 16 + col;            // local out t
        const unsigned short* bp = &xlds[(ntl + kb) * 24 + ci0b];
        #pragma unroll
        for (int s = 0; s < 8; ++s) {
            // k-tap = 2s + kb  ->  +2 rows per s  ->  +48 ushorts
            short8 bfrag = *reinterpret_cast<const short8*>(bp + s * 48);
            acc[nf] = __builtin_amdgcn_mfma_f32_16x16x32_bf16(afrag[s], bfrag, acc[nf], 0, 0, 0);
        }
    }

    // ---- epilogue: D row = co_l = 4*hi2 + r, col = t ----
    const int colb = 4 * hi2;
    float bv[4];
    #pragma unroll
    for (int r = 0; r < 4; ++r) bv[r] = bias[16 * p + colb + r];

    #pragma unroll
    for (int nf = 0; nf < 4; ++nf) {
        int t = t0 + wave * 64 + nf * 16 + col;
        #pragma unroll
        for (int r = 0; r < 4; ++r) {
            int co = 16 * p + colb + r;
            out[((size_t)b * 192 + co) * TLEN + t] = acc[nf][r] + bv[r];
        }
    }
}

extern "C" void kernel_launch(void* const* d_in, const int* in_sizes, int n_in,
                              void* d_out, int out_size, void* d_ws, size_t ws_size,
                              hipStream_t stream) {
    const float* x    = (const float*)d_in[0];
    const float* w    = (const float*)d_in[1];
    const float* bias = (const float*)d_in[2];
    float* out        = (float*)d_out;
    unsigned short* wf = (unsigned short*)d_ws;   // 98304 B

    prep_weights_kernel<<<dim3(192), dim3(256), 0, stream>>>(w, wf);
    skel_conv_kernel<<<dim3(TLEN / TT, NPAIR, BATCH), dim3(256), 0, stream>>>(
        x, wf, bias, out);
}

// Round 4
// 162.598 us; speedup vs baseline: 1.7789x; 1.2437x over previous
//
#include <hip/hip_runtime.h>
#include <stdint.h>

#define TLEN  4096
#define BATCH 128
#define NG    6      // groups: 2 joint-pairs (32 co, 24-ci union) per block
#define TT    256    // output t per block
#define ROWS  272    // 256 + 15 halo; rows >= 270 zeroed (tap-15 pad reads)

typedef short short8 __attribute__((ext_vector_type(8)));
typedef float f32x4 __attribute__((ext_vector_type(4)));
typedef unsigned int uint;

__device__ __forceinline__ unsigned short f2bf(float f) {
    unsigned int u = __float_as_uint(f);
    u += 0x7fffu + ((u >> 16) & 1u);
    return (unsigned short)(u >> 16);
}

// Masked bf16 weight fragments: wf[p][co_l(16)][kk(256)], kk = k*16 + ci_l.
// Pair p covers ci_g = 8p-4 + ci_l (4-joint union). Zero outside skeleton
// mask / bounds / k==15 (taps padded 15->16).
__global__ __launch_bounds__(256) void prep_weights_kernel(
    const float* __restrict__ w, unsigned short* __restrict__ wf)
{
    int e = blockIdx.x * 256 + threadIdx.x;   // 12*16*256 = 49152
    int kk   = e & 255;
    int co_l = (e >> 8) & 15;
    int p    = e >> 12;
    int k    = kk >> 4;
    int ci_l = kk & 15;
    int jo = 2 * p + (co_l >> 3);
    int jn = 2 * p - 1 + (ci_l >> 2);
    int ci_g = 8 * p - 4 + ci_l;
    float v = 0.0f;
    if (k < 15 && jn >= 0 && jn < 24 && jn >= jo - 1 && jn <= jo + 1)
        v = w[((size_t)(16 * p + co_l) * 96 + ci_g) * 15 + k];
    wf[e] = f2bf(v);
}

__global__ __launch_bounds__(256, 4) void skel_conv_kernel(
    const float* __restrict__ x, const unsigned short* __restrict__ wf,
    const float* __restrict__ bias, float* __restrict__ out)
{
    // x tile [row][ci_union 24] bf16, stride 24 ushorts (48 B). 3-unit row
    // stride (gcd(3,8)=1) -> staging b128 writes sweep all 8 bank groups.
    __shared__ __align__(16) unsigned short xlds[ROWS * 24];

    const int tid  = threadIdx.x;
    const int t0   = blockIdx.x * TT;
    const int g    = blockIdx.y;
    const int b    = blockIdx.z;
    const int lane = tid & 63;
    const int wave = tid >> 6;
    const int q     = wave & 1;     // pair within group
    const int thalf = wave >> 1;    // 128-t half
    const int p     = 2 * g + q;    // global pair
    const int col  = lane & 15;     // A row (co) / B,D col (t)
    const int hi2  = lane >> 4;     // K sub-block selector

    // ---- A fragments: 8 K-slices of this wave's pair -> registers, PINNED ----
    short8 afrag[8];
    {
        const unsigned short* wp = wf + (size_t)(p * 16 + col) * 256 + hi2 * 8;
        #pragma unroll
        for (int s = 0; s < 8; ++s)
            afrag[s] = *reinterpret_cast<const short8*>(wp + s * 32);
    }
    // Force residency (R2 failure mode: compiler re-sinks A loads into loop).
    #pragma unroll
    for (int s = 0; s < 8; ++s)
        asm volatile("" : "+v"(afrag[s]));

    // ---- stage x union tile: lane = t-row, coalesced dword loads, 24 ci ----
    {
        const int ciBase = 16 * g - 4;
        const float* xb = x + (size_t)b * 96 * TLEN;
        for (int r = tid; r < ROWS; r += 256) {
            uint vals[12];
            if (r < 270) {
                int tg = t0 - 7 + r;
                int src = tg < 0 ? -tg : (tg >= TLEN ? 2 * TLEN - 2 - tg : tg);
                const float* xs = xb + src;
                #pragma unroll
                for (int qq = 0; qq < 12; ++qq) {
                    int c0 = ciBase + 2 * qq;
                    int c1 = c0 + 1;
                    float f0 = ((unsigned)c0 < 96u) ? xs[(size_t)c0 * TLEN] : 0.f;
                    float f1 = ((unsigned)c1 < 96u) ? xs[(size_t)c1 * TLEN] : 0.f;
                    vals[qq] = (uint)f2bf(f0) | ((uint)f2bf(f1) << 16);
                }
            } else {
                #pragma unroll
                for (int qq = 0; qq < 12; ++qq) vals[qq] = 0u;
            }
            *reinterpret_cast<uint4*>(&xlds[r * 24 + 0]) =
                make_uint4(vals[0], vals[1], vals[2], vals[3]);
            *reinterpret_cast<uint4*>(&xlds[r * 24 + 8]) =
                make_uint4(vals[4], vals[5], vals[6], vals[7]);
            *reinterpret_cast<uint4*>(&xlds[r * 24 + 16]) =
                make_uint4(vals[8], vals[9], vals[10], vals[11]);
        }
    }
    __syncthreads();

    // Pair q's 16-ci window sits at union ushort offset 8q..8q+16.
    const int ci0 = 8 * q + 8 * (hi2 & 1);
    const int kb  = hi2 >> 1;          // k-tap low bit
    const int colb = 4 * hi2;          // D row block

    // ---- acc init = bias (fold the epilogue add into MFMA C-in) ----
    f32x4 acc[8];
    {
        float bv0 = bias[16 * p + colb + 0];
        float bv1 = bias[16 * p + colb + 1];
        float bv2 = bias[16 * p + colb + 2];
        float bv3 = bias[16 * p + colb + 3];
        #pragma unroll
        for (int nf = 0; nf < 8; ++nf)
            acc[nf] = (f32x4){bv0, bv1, bv2, bv3};
    }

    // ---- MFMA: s outer (k-tap pairs), nf inner (8 independent acc chains) ----
    const int rbase = thalf * 128 + col + kb;
    #pragma unroll
    for (int s = 0; s < 8; ++s) {
        const unsigned short* bp = &xlds[(rbase + 2 * s) * 24 + ci0];
        #pragma unroll
        for (int nf = 0; nf < 8; ++nf) {
            short8 bfrag = *reinterpret_cast<const short8*>(bp + nf * (16 * 24));
            acc[nf] = __builtin_amdgcn_mfma_f32_16x16x32_bf16(afrag[s], bfrag, acc[nf], 0, 0, 0);
        }
    }

    // ---- store: D row = colb + r, col = t ----
    float* ob = out + ((size_t)b * 192 + 16 * p + colb) * TLEN
              + t0 + thalf * 128 + col;
    #pragma unroll
    for (int nf = 0; nf < 8; ++nf) {
        #pragma unroll
        for (int r = 0; r < 4; ++r)
            ob[(size_t)r * TLEN + nf * 16] = acc[nf][r];
    }
}

extern "C" void kernel_launch(void* const* d_in, const int* in_sizes, int n_in,
                              void* d_out, int out_size, void* d_ws, size_t ws_size,
                              hipStream_t stream) {
    const float* x    = (const float*)d_in[0];
    const float* w    = (const float*)d_in[1];
    const float* bias = (const float*)d_in[2];
    float* out        = (float*)d_out;
    unsigned short* wf = (unsigned short*)d_ws;   // 98304 B

    prep_weights_kernel<<<dim3(192), dim3(256), 0, stream>>>(w, wf);
    skel_conv_kernel<<<dim3(TLEN / TT, NG, BATCH), dim3(256), 0, stream>>>(
        x, wf, bias, out);
}